// Round 1
// 105.471 us; speedup vs baseline: 1.0214x; 1.0214x over previous
//
#include <hip/hip_runtime.h>
#include <stdint.h>

// DEQ: z_{t+1} = tanh(c + z_t @ B_w^T), c = x@A_w^T + A_b + B_b (fp32, computed once).
// ||B_w||_2 ~= 0.115 -> contraction; 5 Picard applications converge to ~6e-6 in y.
//
// Transposed MFMA, now 16x16x16_f16: z^T[s][b] = sum_k B_w[s][k] z^T[k][b].
//   KEY LAYOUT IDENTITY (this round's change): for 16x16x16 the B-operand
//   layout (k = quad*4+j, n = lane&15) is IDENTICAL to the C/D accumulator
//   layout (row = quad*4+r, col = lane&15). So acc tile mt, after tanh +
//   cvt_pkrtz, IS the B-fragment for K-tile kt=mt. The entire cross-lane
//   rebuild (64 ds_bpermute + 16 selects per application, 3.1M LDS bank
//   conflict cycles) is deleted. No LDS / cross-lane ops in the loop.
// Cost: 64 MFMAs per application (8 mt x 8 kt) instead of 32 — acceptable at
//   MfmaUtil 12%.

typedef _Float16 half4  __attribute__((ext_vector_type(4)));
typedef __fp16   fp16x2 __attribute__((ext_vector_type(2)));  // cvt_pkrtz native type
typedef float    f32x4  __attribute__((ext_vector_type(4)));

#define BW_STRIDE 136   // f16 elems per staged B_w row (one-time staging only)

union H2U { fp16x2 h; uint32_t u; };
union H4U { half4 h; uint32_t u[2]; };

__device__ __forceinline__ float tanh_fast(float v) {
    // tanh(v) = 1 - 2/(e^{2v}+1); v_exp_f32 + v_rcp_f32 (~1 ulp each)
    float e2 = __builtin_amdgcn_exp2f(v * 2.8853900817779268f); // 2*log2(e)
    return 1.0f - 2.0f * __builtin_amdgcn_rcpf(e2 + 1.0f);
}

__global__ __launch_bounds__(256, 2)
void deq_solve_kernel(const float* __restrict__ xin,
                      const float* __restrict__ A_w,
                      const float* __restrict__ A_b,
                      const float* __restrict__ B_w,
                      const float* __restrict__ B_b,
                      const float* __restrict__ h_w,
                      const float* __restrict__ h_b,
                      float* __restrict__ out)
{
    __shared__ __align__(16) _Float16 sb[128 * BW_STRIDE];

    const int tid  = threadIdx.x;
    const int lane = tid & 63;
    const int wv   = tid >> 6;
    const int quad = lane >> 4;
    const int bcol = lane & 15;

    // ---- one-time: stage B_w fp32 -> f16 LDS (coalesced float4) ----
    for (int i = tid; i < 4096; i += 256) {
        f32x4 v = ((const f32x4*)B_w)[i];
        int row = i >> 5, col = (i & 31) << 2;
        H2U h0, h1;
        h0.h = __builtin_amdgcn_cvt_pkrtz(v[0], v[1]);
        h1.h = __builtin_amdgcn_cvt_pkrtz(v[2], v[3]);
        *(uint32_t*)(sb + row * BW_STRIDE + col)     = h0.u;
        *(uint32_t*)(sb + row * BW_STRIDE + col + 2) = h1.u;
    }
    __syncthreads();

    // ---- constant A fragments (16x16x16 layout): ----
    //   af[mt][kt] lane (quad,bcol) holds A[m=bcol][k=quad*4+j], j=0..3
    //   i.e. B_w[mt*16 + bcol][kt*16 + quad*4 + j]  (half4 = 2 VGPRs)
    half4 af[8][8];
    #pragma unroll
    for (int mt = 0; mt < 8; ++mt)
        #pragma unroll
        for (int kt = 0; kt < 8; ++kt)
            af[mt][kt] = *(const half4*)(sb + (mt * 16 + bcol) * BW_STRIDE + kt * 16 + quad * 4);

    // ---- c = x@A_w^T + A_b + B_b, fp32, in C-layout (computed once) ----
    const int gb = blockIdx.x * 64 + wv * 16 + bcol;
    const f32x4 xv = *(const f32x4*)(xin + 4 * gb);
    f32x4 cf[8];
    #pragma unroll
    for (int mt = 0; mt < 8; ++mt) {
        #pragma unroll
        for (int r = 0; r < 4; ++r) {
            int s = mt * 16 + quad * 4 + r;
            f32x4 aw = *(const f32x4*)(A_w + 4 * s);
            cf[mt][r] = A_b[s] + B_b[s] + aw[0]*xv[0] + aw[1]*xv[1] + aw[2]*xv[2] + aw[3]*xv[3];
        }
    }

    half4 bf[8];   // B-fragments == tanh(acc) packed; bf[kt] comes from acc[mt=kt]

#define EPILOGUE(ACC)                                                      \
    _Pragma("unroll")                                                      \
    for (int mt = 0; mt < 8; ++mt) {                                       \
        H2U pa, pb;                                                        \
        pa.h = __builtin_amdgcn_cvt_pkrtz(tanh_fast((ACC)[mt][0]),         \
                                          tanh_fast((ACC)[mt][1]));        \
        pb.h = __builtin_amdgcn_cvt_pkrtz(tanh_fast((ACC)[mt][2]),         \
                                          tanh_fast((ACC)[mt][3]));        \
        H4U w; w.u[0] = pa.u; w.u[1] = pb.u;                               \
        bf[mt] = w.h;                                                      \
    }

#define MFMA_CHAIN(ACC)                                                    \
    _Pragma("unroll")                                                      \
    for (int mt = 0; mt < 8; ++mt)                                         \
        (ACC)[mt] = __builtin_amdgcn_mfma_f32_16x16x16f16(af[mt][0], bf[0], cf[mt], 0, 0, 0); \
    _Pragma("unroll")                                                      \
    for (int kt = 1; kt < 8; ++kt)                                         \
        _Pragma("unroll")                                                  \
        for (int mt = 0; mt < 8; ++mt)                                     \
            (ACC)[mt] = __builtin_amdgcn_mfma_f32_16x16x16f16(af[mt][kt], bf[kt], (ACC)[mt], 0, 0, 0);

    // ---- application 1: z1 = tanh(c) ----
    EPILOGUE(cf)

    // ---- applications 2..4 ----
    #pragma unroll 1
    for (int it = 0; it < 3; ++it) {
        f32x4 acc[8];
        MFMA_CHAIN(acc)
        EPILOGUE(acc)
    }

    // ---- application 5 fused with output: y = h_w . tanh(acc) + h_b ----
    float partial = 0.f;
    {
        f32x4 acc[8];
        MFMA_CHAIN(acc)
        #pragma unroll
        for (int mt = 0; mt < 8; ++mt) {
            f32x4 hw = *(const f32x4*)(h_w + mt * 16 + quad * 4);
            #pragma unroll
            for (int r = 0; r < 4; ++r)
                partial += tanh_fast(acc[mt][r]) * hw[r];
        }
    }
    partial += __shfl_xor(partial, 16);
    partial += __shfl_xor(partial, 32);
    if (quad == 0)
        out[gb] = partial + h_b[0];
}

extern "C" void kernel_launch(void* const* d_in, const int* in_sizes, int n_in,
                              void* d_out, int out_size, void* d_ws, size_t ws_size,
                              hipStream_t stream) {
    const float* x   = (const float*)d_in[0];
    const float* A_w = (const float*)d_in[1];
    const float* A_b = (const float*)d_in[2];
    const float* B_w = (const float*)d_in[3];
    const float* B_b = (const float*)d_in[4];
    const float* h_w = (const float*)d_in[5];
    const float* h_b = (const float*)d_in[6];
    float* outp = (float*)d_out;

    int batch = in_sizes[0] / 4;   // 131072
    int grid  = batch / 64;        // 64 batch rows per block (4 waves x 16)
    deq_solve_kernel<<<grid, 256, 0, stream>>>(x, A_w, A_b, B_w, B_b, h_w, h_b, outp);
}